// Round 6
// baseline (269.652 us; speedup 1.0000x reference)
//
#include <hip/hip_runtime.h>

// Patch_Embed_Center_Rotate: x (256,3,224,224) f32, P=16, grid 14x14.
// out = x everywhere, except patches with grid col j in [5,9] AND grid row
// k in [5,9], which are transposed within the 16x16 patch:
//   out[b,c, k*16+a3, j*16+a4] = x[b,c, k*16+a4, j*16+a3]
//
// v6: external-reference structure. Bulk move = runtime D2D blit via
// hipMemcpyAsync (graph-capture-legal per harness rules; documented ~85%
// of peak, and this trace's fills sustain 6.5 TB/s on this buffer). Then a
// small sequential fixup kernel re-reads the 19.6 MB center region from x,
// transposes each 16x16 patch through LDS (v5's center role: f4-coalesced
// nt loads, 2-way-free bank scatter, 16B-aligned ds_read_b128, f4 nt
// stores), and overwrites the center of out. Double-writes the center
// (+19.6 MB ~ +3 us) in exchange for a hole-free, div/mod-free bulk copy.
// Round 2-5 evidence: in-kernel levers (occupancy shape, role split, LDS
// path) are all <= noise; only nt hints moved the needle (~16 us). Hand
// kernel ~60-65 us vs 47 us copy floor -> this tests whether AMD's tuned
// blit closes the gap. Falsifier: SDMA-mapped memcpy -> dur blows up,
// revert to v5.

#define IMG_F 50176          // 224*224 floats per (b,c) image
#define TOTAL_BYTES ((size_t)256 * 3 * 224 * 224 * 4)  // 154,140,672

typedef float vf4 __attribute__((ext_vector_type(4)));

__global__ __launch_bounds__(256) void center_fixup(
    const float* __restrict__ x, float* __restrict__ out) {
  // one 64-lane wave per 16x16 center patch, 4 patches per block.
  __shared__ float ldsT[4][16][20];          // [patch][out-row][out-col]
  const int lp = threadIdx.x >> 6;           // local patch 0..3
  const int l  = threadIdx.x & 63;           // lane
  const int p  = blockIdx.x * 4 + lp;        // global center patch 0..19199
  const int q  = p / 25;                     // (b,c) image 0..767
  const int pi = p % 25;
  const int kk = 5 + pi / 5;                 // grid row 5..9
  const int jj = 5 + pi % 5;                 // grid col 5..9
  const float* __restrict__ xs = x + (size_t)q * IMG_F;
  float* __restrict__ os = out + (size_t)q * IMG_F;

  const int r  = l >> 2;                     // row within patch 0..15
  const int c0 = (l & 3) << 2;               // first col within patch

  // coalesced f4 load of patch row r, cols c0..c0+3 (no reuse -> nt)
  const vf4 v = __builtin_nontemporal_load(
      (const vf4*)(xs + (kk * 16 + r) * 224 + jj * 16 + c0));
  // scatter transposed; banks (c*20 + r) mod 32 -> exactly 2 lanes/bank (free)
  ldsT[lp][c0 + 0][r] = v.x;
  ldsT[lp][c0 + 1][r] = v.y;
  ldsT[lp][c0 + 2][r] = v.z;
  ldsT[lp][c0 + 3][r] = v.w;

  __syncthreads();

  // 16B-aligned LDS row read, coalesced full-line nt store over the
  // blit-written center (sequential on stream -> no ordering hazard).
  vf4 w;
  w.x = ldsT[lp][r][c0 + 0];
  w.y = ldsT[lp][r][c0 + 1];
  w.z = ldsT[lp][r][c0 + 2];
  w.w = ldsT[lp][r][c0 + 3];
  __builtin_nontemporal_store(
      w, (vf4*)(os + (kk * 16 + r) * 224 + jj * 16 + c0));
}

extern "C" void kernel_launch(void* const* d_in, const int* in_sizes, int n_in,
                              void* d_out, int out_size, void* d_ws, size_t ws_size,
                              hipStream_t stream) {
  const float* x = (const float*)d_in[0];
  float* out = (float*)d_out;
  // bulk move: full image, including (stale) center; fixup overwrites it.
  hipMemcpyAsync(out, x, TOTAL_BYTES, hipMemcpyDeviceToDevice, stream);
  // 19200 center patches, 4 per block.
  center_fixup<<<4800, 256, 0, stream>>>(x, out);
}

// Round 7
// 258.390 us; speedup vs baseline: 1.0436x; 1.0436x over previous
//
#include <hip/hip_runtime.h>

// Patch_Embed_Center_Rotate: x (256,3,224,224) f32, P=16, grid 14x14.
// out = x everywhere, except patches with grid col j in [5,9] AND grid row
// k in [5,9], which are transposed within the 16x16 patch:
//   out[b,c, k*16+a3, j*16+a4] = x[b,c, k*16+a4, j*16+a3]
//
// v7: two hand-written dispatches (v6 proved the overwrite structure; its
// regression was hipMemcpyAsync itself, which never showed as a fast blit).
//  1) pure_copy: branch-free, div/mod-free, hole-free nt float4 copy of the
//     full 147 MB (stale center included). Structurally identical to the
//     6.29 TB/s m13 copy probe: one f4 per thread, every wave a full 1KB
//     coalesced line. This removes v4.1's per-thread div/mod + center
//     branch + complementary-masked ragged stores in rows 80..159.
//  2) center_fixup (verified in v5/v6): one wave per 16x16 center patch,
//     f4 nt-load -> LDS transpose (2-way-free banks, 16B-aligned reads) ->
//     f4 nt-store overwriting the stale center. +19.6 MB double-write
//     (~3 us) for a hole-free bulk stream.
// Sequential dispatches on the stream give the write-after-write ordering.
// Ledger (fill-normalized kernel time): v4.1=60, v5=65, v6(memcpy)=80,
// floor=47+fixup~8. Prediction: ~55-58 -> dur_us ~247. Falsifier: >=258
// means holes/branches never limited us -> restore v4.1, declare ceiling.

#define IMG_F 50176          // 224*224 floats per (b,c) image
#define N_F4 9633792         // 256*3*224*224/4 float4s

typedef float vf4 __attribute__((ext_vector_type(4)));

__global__ __launch_bounds__(256) void pure_copy(
    const float* __restrict__ x, float* __restrict__ out) {
  const int idx = blockIdx.x * 256 + threadIdx.x;  // exact grid: no bound check
  vf4 v = __builtin_nontemporal_load((const vf4*)x + idx);
  __builtin_nontemporal_store(v, (vf4*)out + idx);
}

__global__ __launch_bounds__(256) void center_fixup(
    const float* __restrict__ x, float* __restrict__ out) {
  // one 64-lane wave per 16x16 center patch, 4 patches per block.
  __shared__ float ldsT[4][16][20];          // [patch][out-row][out-col]
  const int lp = threadIdx.x >> 6;           // local patch 0..3
  const int l  = threadIdx.x & 63;           // lane
  const int p  = blockIdx.x * 4 + lp;        // global center patch 0..19199
  const int q  = p / 25;                     // (b,c) image 0..767
  const int pi = p % 25;
  const int kk = 5 + pi / 5;                 // grid row 5..9
  const int jj = 5 + pi % 5;                 // grid col 5..9
  const float* __restrict__ xs = x + (size_t)q * IMG_F;
  float* __restrict__ os = out + (size_t)q * IMG_F;

  const int r  = l >> 2;                     // row within patch 0..15
  const int c0 = (l & 3) << 2;               // first col within patch

  // coalesced f4 load of patch row r, cols c0..c0+3 (no reuse -> nt)
  const vf4 v = __builtin_nontemporal_load(
      (const vf4*)(xs + (kk * 16 + r) * 224 + jj * 16 + c0));
  // scatter transposed; banks (c*20 + r) mod 32 -> exactly 2 lanes/bank (free)
  ldsT[lp][c0 + 0][r] = v.x;
  ldsT[lp][c0 + 1][r] = v.y;
  ldsT[lp][c0 + 2][r] = v.z;
  ldsT[lp][c0 + 3][r] = v.w;

  __syncthreads();

  // 16B-aligned LDS row read, coalesced full-line nt store over the
  // copy-written stale center (sequential dispatch -> no ordering hazard).
  vf4 w;
  w.x = ldsT[lp][r][c0 + 0];
  w.y = ldsT[lp][r][c0 + 1];
  w.z = ldsT[lp][r][c0 + 2];
  w.w = ldsT[lp][r][c0 + 3];
  __builtin_nontemporal_store(
      w, (vf4*)(os + (kk * 16 + r) * 224 + jj * 16 + c0));
}

extern "C" void kernel_launch(void* const* d_in, const int* in_sizes, int n_in,
                              void* d_out, int out_size, void* d_ws, size_t ws_size,
                              hipStream_t stream) {
  const float* x = (const float*)d_in[0];
  float* out = (float*)d_out;
  pure_copy<<<N_F4 / 256, 256, 0, stream>>>(x, out);   // 37632 blocks
  center_fixup<<<4800, 256, 0, stream>>>(x, out);      // 19200 center patches
}

// Round 8
// 252.439 us; speedup vs baseline: 1.0682x; 1.0236x over previous
//
#include <hip/hip_runtime.h>

// Patch_Embed_Center_Rotate: x (256,3,224,224) f32, P=16, grid 14x14.
// out = x everywhere, except patches with grid col j in [5,9] AND grid row
// k in [5,9], which are transposed within the 16x16 patch:
//   out[b,c, k*16+a3, j*16+a4] = x[b,c, k*16+a4, j*16+a3]
//
// v8 = v4.1 (best measured: one thread per f4, predicated center-gather in
// the same pass, ~60 us fill-normalized) with ONE variable changed:
// identity-path LOADS are plain/cached again; only STORES keep the
// nontemporal hint. Mechanism: the fast harness fills (6.5 TB/s) are
// write-only + no write-allocate; m13's 6.29 TB/s copy probe used plain
// cached loads. v7's all-nt pure copy managed only ~5 TB/s -> suspect
// load-side nt bypasses read-side L2 buffering and costs read BW, while
// store-side nt (no write-allocate) was the whole +16 us of round 4.
// If neutral: ~4.9 TB/s is the read+write concurrency ceiling for this
// pattern on this machine -> declare roofline with the best variant.

#define HH 224
#define WW 224
#define W4 56  // 224/4

typedef float vf4 __attribute__((ext_vector_type(4)));

__global__ __launch_bounds__(256) void patch_rotate_kernel(
    const float* __restrict__ x, float* __restrict__ out, int n4) {
  int idx = blockIdx.x * blockDim.x + threadIdx.x;  // float4 index into out
  if (idx >= n4) return;

  int bc   = idx / (HH * W4);   // fused (b,c)
  int rem  = idx % (HH * W4);
  int row  = rem / W4;          // 0..223
  int col4 = rem % W4;          // 0..55

  int k = row >> 4;     // grid row
  int j = col4 >> 2;    // grid col  (col4*4/16)

  bool center = (j >= 5) & (j <= 9) & (k >= 5) & (k <= 9);

  if (!center) {
    // identity: plain cached load (read BW), nontemporal store only
    // (no write-allocate -- the proven win from round 4).
    vf4 v = *((const vf4*)x + idx);
    __builtin_nontemporal_store(v, (vf4*)out + idx);
  } else {
    // transposed patch: out col a4 -> src row k*16+a4; out row a3 -> src col.
    // Scattered 4B cached loads; L2 merges the 16 lanes sharing each 64B line.
    int a3  = row & 15;
    int a4b = (col4 & 3) << 2;            // first of 4 a4 values
    int base = (bc * HH + (k << 4)) * WW + (j << 4) + a3;  // a4 = 0 element
    vf4 v;
    v.x = x[base + (a4b + 0) * WW];
    v.y = x[base + (a4b + 1) * WW];
    v.z = x[base + (a4b + 2) * WW];
    v.w = x[base + (a4b + 3) * WW];
    __builtin_nontemporal_store(v, (vf4*)out + idx);
  }
}

extern "C" void kernel_launch(void* const* d_in, const int* in_sizes, int n_in,
                              void* d_out, int out_size, void* d_ws, size_t ws_size,
                              hipStream_t stream) {
  const float* x = (const float*)d_in[0];
  float* out = (float*)d_out;
  int n4 = out_size / 4;                       // 9,633,792 float4s
  int threads = 256;
  int blocks = (n4 + threads - 1) / threads;   // 37,632
  patch_rotate_kernel<<<blocks, threads, 0, stream>>>(x, out, n4);
}